// Round 14
// baseline (420.104 us; speedup 1.0000x reference)
//
#include <hip/hip_runtime.h>
#include <math.h>

#define NN 100000      // nodes
#define CD 32          // classes / hidden
#define NPB 4          // nodes (waves) per block in gather kernel
#define NREP 8         // rank-counter replicas (per-line contention /8)

#define NKEY2 (NN * NREP)                              // 800k (node,rep) keys
#define SC_EPB 512
#define SC_NB  ((NKEY2 + SC_EPB - 1) / SC_EPB)         // 1563 scan blocks

typedef unsigned int   uint32;
typedef unsigned short ushort16;

// fp32 -> bf16 round-to-nearest-even
__device__ __forceinline__ ushort16 f2b(float f) {
    uint32 u = __float_as_uint(f);
    u = (u + 0x7FFFu + ((u >> 16) & 1u)) >> 16;
    return (ushort16)u;
}
// packed bf16 pair -> two fp32 (exact)
__device__ __forceinline__ float b2f_lo(uint32 u) { return __uint_as_float(u << 16); }
__device__ __forceinline__ float b2f_hi(uint32 u) { return __uint_as_float(u & 0xFFFF0000u); }

// ---------------------------------------------------------------------------
__global__ void detect_idx64(const void* edge, int* flag) {
    const long long* p = (const long long*)edge;
    int lane = threadIdx.x & 63;
    int bad = 0;
    for (int i = lane; i < 512; i += 64) {
        long long v = p[i];
        if (v < 0 || v >= NN) bad = 1;
    }
    unsigned long long anybad = __ballot(bad);
    if (lane == 0) *flag = (anybad == 0ULL) ? 1 : 0;
}

__device__ __forceinline__ int load_idx(const void* edge, int i, int is64) {
    if (is64) return (int)((const long long*)edge)[i];
    return ((const int*)edge)[i];
}

// ---------------------------------------------------------------------------
// x (fp32, NN x 50) -> packed bf16 rows, stride 26 uints (uint 25 = zero pad).
__global__ void cvt_x_kernel(const float* __restrict__ x, uint32* __restrict__ xb) {
    const int t = blockIdx.x * blockDim.x + threadIdx.x;
    if (t >= NN * 26) return;
    const int n = t / 26;
    const int c = t - n * 26;
    if (c == 25) { xb[t] = 0; return; }
    float2 v = *(const float2*)&x[n * 50 + 2 * c];
    xb[t] = (uint32)f2b(v.x) | ((uint32)f2b(v.y) << 16);
}

// ---------------------------------------------------------------------------
// CSR build: single atomic pass over REPLICATED counters (replica-major:
// counts2[r*NN+d]); R13 showed packed counters serialize ~256 atomics/line
// cross-XCD. rank[e] = rank within (dst, replica) group.
__global__ void rank_kernel(const void* edge, int E, const int* flag,
                            int* counts2, int* __restrict__ rank) {
    const int is64 = *flag;
    const int r    = blockIdx.x & (NREP - 1);
    int* cnt = counts2 + (size_t)r * NN;
    const int e0   = blockIdx.x * (blockDim.x * 8) + threadIdx.x;
    int  d[8], rk[8];
    bool v[8];
#pragma unroll
    for (int k = 0; k < 8; ++k) {
        int e = e0 + k * 256;
        v[k] = e < E;
        if (v[k]) d[k] = load_idx(edge, E + e, is64);
    }
#pragma unroll
    for (int k = 0; k < 8; ++k)
        if (v[k]) rk[k] = atomicAdd(&cnt[d[k]], 1);
#pragma unroll
    for (int k = 0; k < 8; ++k)
        if (v[k]) rank[e0 + k * 256] = rk[k];
}

// Scan over NKEY2 keys in (node, replica) order; key i -> counts2[(i&7)*NN + (i>>3)].
__device__ __forceinline__ int key_count(const int* counts2, int i) {
    return counts2[(size_t)(i & (NREP - 1)) * NN + (i >> 3)];
}

__global__ void scan_partial_kernel(const int* __restrict__ counts2,
                                    int* __restrict__ blockSums) {
    __shared__ int red[256];
    const int b = blockIdx.x, t = threadIdx.x;
    const int base = b * SC_EPB + t * 2;
    int s = 0;
    if (base < NKEY2)     s += key_count(counts2, base);
    if (base + 1 < NKEY2) s += key_count(counts2, base + 1);
    red[t] = s;
    __syncthreads();
    for (int off = 128; off > 0; off >>= 1) {
        if (t < off) red[t] += red[t + off];
        __syncthreads();
    }
    if (t == 0) blockSums[b] = red[0];
}

// Chunked exclusive scan of SC_NB block sums (single block).
__global__ void scan_bases_kernel(int* blockSums) {
    __shared__ int part[256];
    const int t = threadIdx.x;
    const int CH = (SC_NB + 255) / 256;      // 7
    const int b0 = t * CH;
    const int b1 = min(b0 + CH, SC_NB);
    int s = 0;
    for (int i = b0; i < b1; ++i) s += blockSums[i];
    part[t] = s;
    __syncthreads();
    if (t == 0) {
        int run = 0;
        for (int i = 0; i < 256; ++i) { int v = part[i]; part[i] = run; run += v; }
    }
    __syncthreads();
    int run = part[t];
    for (int i = b0; i < b1; ++i) { int v = blockSums[i]; blockSums[i] = run; run += v; }
}

__global__ void scan_final_kernel(const int* __restrict__ counts2,
                                  const int* __restrict__ blockSums,
                                  int* __restrict__ keyoff) {
    __shared__ int tsum[256];
    const int b = blockIdx.x, t = threadIdx.x;
    const int base = b * SC_EPB + t * 2;
    const int c0 = (base < NKEY2)     ? key_count(counts2, base)     : 0;
    const int c1 = (base + 1 < NKEY2) ? key_count(counts2, base + 1) : 0;
    tsum[t] = c0 + c1;
    __syncthreads();
    for (int off = 1; off < 256; off <<= 1) {
        int u = (t >= off) ? tsum[t - off] : 0;
        __syncthreads();
        tsum[t] += u;
        __syncthreads();
    }
    const int bbase = blockSums[b];
    const int excl  = tsum[t] - (c0 + c1);
    if (base < NKEY2) {
        keyoff[base] = bbase + excl;
        if (base + 1 < NKEY2) keyoff[base + 1] = bbase + excl + c0;
    }
    if (b == SC_NB - 1 && t == 255) keyoff[NKEY2] = bbase + tsum[255];  // == E
}

// place: NO atomics — pos = keyoff[d*8 + r] + rank[e], with r recomputed as
// the rank-pass block id (e >> 11) & 7 (same grid/batch layout).
__global__ void place_kernel(const void* edge, int E, const int* flag,
                             const int* __restrict__ keyoff,
                             const int* __restrict__ rank,
                             int* __restrict__ csr_src) {
    const int is64 = *flag;
    const int e0   = blockIdx.x * (blockDim.x * 8) + threadIdx.x;
    const int r    = blockIdx.x & (NREP - 1);
#pragma unroll
    for (int k = 0; k < 8; ++k) {
        int e = e0 + k * 256;
        if (e < E) {
            int s = load_idx(edge, e, is64);
            int d = load_idx(edge, E + e, is64);
            csr_src[keyoff[d * NREP + r] + rank[e]] = s;
        }
    }
}

// ---------------------------------------------------------------------------
// Gather-max kernel (bf16, R11-proven). One 64-lane wave per node; 2 edges
// per wave (halves) x unroll4 = 8 loads in flight. Node n's CSR segment is
// [keyoff[8n], keyoff[8n+8]).
template <int CW, int RSTR>
__global__ void gather_kernel(const uint32* __restrict__ hb,
                              const int* __restrict__ keyoff,
                              const int* __restrict__ csr_src,
                              uint32* __restrict__ aggB) {
    const int tid  = threadIdx.x;
    const int g    = tid >> 6;
    const int lane = tid & 63;
    const int p    = lane >> 5;
    const int j    = lane & 31;
    const bool ac  = (j < CW);
    const int n    = blockIdx.x * NPB + g;
    if (n >= NN) return;

    const float NEG = -INFINITY;
    const int beg = keyoff[n * NREP];
    const int end = keyoff[n * NREP + NREP];

    float l0 = NEG, h0 = NEG, l1 = NEG, h1 = NEG;
    float l2 = NEG, h2 = NEG, l3 = NEG, h3 = NEG;
    int i = beg + p;
    for (; i + 6 < end; i += 8) {
        int s0 = csr_src[i];
        int s1 = csr_src[i + 2];
        int s2 = csr_src[i + 4];
        int s3 = csr_src[i + 6];
        if (ac) {
            uint32 u0 = hb[(size_t)s0 * RSTR + j];
            uint32 u1 = hb[(size_t)s1 * RSTR + j];
            uint32 u2 = hb[(size_t)s2 * RSTR + j];
            uint32 u3 = hb[(size_t)s3 * RSTR + j];
            l0 = fmaxf(l0, b2f_lo(u0)); h0 = fmaxf(h0, b2f_hi(u0));
            l1 = fmaxf(l1, b2f_lo(u1)); h1 = fmaxf(h1, b2f_hi(u1));
            l2 = fmaxf(l2, b2f_lo(u2)); h2 = fmaxf(h2, b2f_hi(u2));
            l3 = fmaxf(l3, b2f_lo(u3)); h3 = fmaxf(h3, b2f_hi(u3));
        }
    }
    if (ac) {
        if (i < end) {
            uint32 u = hb[(size_t)csr_src[i] * RSTR + j];
            l0 = fmaxf(l0, b2f_lo(u)); h0 = fmaxf(h0, b2f_hi(u));
        }
        if (i + 2 < end) {
            uint32 u = hb[(size_t)csr_src[i + 2] * RSTR + j];
            l1 = fmaxf(l1, b2f_lo(u)); h1 = fmaxf(h1, b2f_hi(u));
        }
        if (i + 4 < end) {
            uint32 u = hb[(size_t)csr_src[i + 4] * RSTR + j];
            l2 = fmaxf(l2, b2f_lo(u)); h2 = fmaxf(h2, b2f_hi(u));
        }
    }
    float lo = fmaxf(fmaxf(l0, l1), fmaxf(l2, l3));
    float hi = fmaxf(fmaxf(h0, h1), fmaxf(h2, h3));
    lo = fmaxf(lo, __shfl_xor(lo, 32));
    hi = fmaxf(hi, __shfl_xor(hi, 32));
    lo = (lo == NEG) ? 0.0f : lo;                 // empty segment -> 0
    hi = (hi == NEG) ? 0.0f : hi;
    if (p == 0 && ac) {
        aggB[(size_t)n * RSTR + j] =
            (__float_as_uint(lo) >> 16) | (__float_as_uint(hi) & 0xFFFF0000u);
    }
}

// ---------------------------------------------------------------------------
// Dense kernel (R11-proven): one lane per node; 32 fp32 accumulators; wave-
// uniform weight addresses scalarize to s_load. MODE 0 = relu -> bf16;
// 2 = log_softmax -> fp32 (lane-local epilogue).
template <int DIN, int ASTR, int HSTR, int OSTR, int MODE>
__global__ void dense_kernel(const uint32* __restrict__ aggB,
                             const uint32* __restrict__ hB,
                             const float* __restrict__ Wl,
                             const float* __restrict__ bl,
                             const float* __restrict__ Wr,
                             void* __restrict__ out_v) {
    const int n = blockIdx.x * blockDim.x + threadIdx.x;
    if (n >= NN) return;

    float acc[CD];
#pragma unroll
    for (int j = 0; j < CD; ++j) acc[j] = bl[j];

    {
        const uint32* row = aggB + (size_t)n * ASTR;
        for (int c = 0; c < DIN / 4; ++c) {
            uint2 u = *(const uint2*)&row[c * 2];
            float d0 = b2f_lo(u.x), d1 = b2f_hi(u.x);
            float d2 = b2f_lo(u.y), d3 = b2f_hi(u.y);
            const float* w = Wl + c * 4 * CD;
#pragma unroll
            for (int j = 0; j < CD; ++j)
                acc[j] += d0 * w[j] + d1 * w[CD + j] + d2 * w[2 * CD + j] + d3 * w[3 * CD + j];
        }
        if (DIN % 4) {
            uint32 u = row[(DIN / 4) * 2];
            float d0 = b2f_lo(u), d1 = b2f_hi(u);
            const float* w = Wl + (DIN - 2) * CD;
#pragma unroll
            for (int j = 0; j < CD; ++j)
                acc[j] += d0 * w[j] + d1 * w[CD + j];
        }
    }
    {
        const uint32* row = hB + (size_t)n * HSTR;
        for (int c = 0; c < DIN / 4; ++c) {
            uint2 u = *(const uint2*)&row[c * 2];
            float d0 = b2f_lo(u.x), d1 = b2f_hi(u.x);
            float d2 = b2f_lo(u.y), d3 = b2f_hi(u.y);
            const float* w = Wr + c * 4 * CD;
#pragma unroll
            for (int j = 0; j < CD; ++j)
                acc[j] += d0 * w[j] + d1 * w[CD + j] + d2 * w[2 * CD + j] + d3 * w[3 * CD + j];
        }
        if (DIN % 4) {
            uint32 u = row[(DIN / 4) * 2];
            float d0 = b2f_lo(u), d1 = b2f_hi(u);
            const float* w = Wr + (DIN - 2) * CD;
#pragma unroll
            for (int j = 0; j < CD; ++j)
                acc[j] += d0 * w[j] + d1 * w[CD + j];
        }
    }

    if (MODE == 0) {
        uint32* orow = (uint32*)out_v + (size_t)n * OSTR;
#pragma unroll
        for (int c = 0; c < CD / 2; ++c) {
            float a0 = fmaxf(acc[2 * c],     0.0f);
            float a1 = fmaxf(acc[2 * c + 1], 0.0f);
            orow[c] = (uint32)f2b(a0) | ((uint32)f2b(a1) << 16);
        }
    } else {
        float m = acc[0];
#pragma unroll
        for (int j = 1; j < CD; ++j) m = fmaxf(m, acc[j]);
        float s = 0.0f;
#pragma unroll
        for (int j = 0; j < CD; ++j) s += expf(acc[j] - m);
        const float lse = m + logf(s);
        float* orow = (float*)out_v + (size_t)n * CD;
#pragma unroll
        for (int j = 0; j < CD; ++j) orow[j] = acc[j] - lse;
    }
}

// ---------------------------------------------------------------------------
extern "C" void kernel_launch(void* const* d_in, const int* in_sizes, int n_in,
                              void* d_out, int out_size, void* d_ws, size_t ws_size,
                              hipStream_t stream) {
    const float* x    = (const float*)d_in[0];
    const void*  edge = d_in[1];
    const float* Wl1 = (const float*)d_in[2];
    const float* bl1 = (const float*)d_in[3];
    const float* Wr1 = (const float*)d_in[4];
    const float* Wl2 = (const float*)d_in[5];
    const float* bl2 = (const float*)d_in[6];
    const float* Wr2 = (const float*)d_in[7];
    const float* Wl3 = (const float*)d_in[8];
    const float* bl3 = (const float*)d_in[9];
    const float* Wr3 = (const float*)d_in[10];

    const int E = in_sizes[1] / 2;

    // Workspace (256B aligned), ≈ 29.8 MB.
    // rank[] lives in d_out (dead before agg1 is written there); h2b reuses
    // xb (dead after dense-L1); agg3 reuses h1b (dead after dense-L2).
    char* ws = (char*)d_ws;
    size_t off = 0;
    auto carve = [&](size_t bytes) {
        void* p = ws + off;
        off = (off + bytes + 255) & ~(size_t)255;
        return p;
    };
    int*    counts2   = (int*)   carve((size_t)NN * NREP * 4);      // 3.2 MB
    int*    keyoff    = (int*)   carve(((size_t)NKEY2 + 1) * 4);    // 3.2 MB
    int*    flag      = (int*)   carve(4);
    int*    blockSums = (int*)   carve((size_t)SC_NB * 4);
    int*    csr_src   = (int*)   carve((size_t)E * 4);              // 6.4 MB
    uint32* xb        = (uint32*)carve((size_t)NN * 26 * 4);        // 10.4 MB
    uint32* h1b       = (uint32*)carve((size_t)NN * 16 * 4);        // 6.4 MB
    (void)ws_size; (void)n_in; (void)out_size;

    int*    rank = (int*)d_out;            // 6.4 MB, dead before agg1
    uint32* agg1 = (uint32*)d_out;         // L1 agg, stride 26
    uint32* agg2 = (uint32*)d_out;         // L2 agg, stride 16
    uint32* h2b  = xb;                     // xb dead after dense-L1
    uint32* agg3 = h1b;                    // h1b dead after dense-L2

    hipMemsetAsync(counts2, 0, (size_t)NN * NREP * 4, stream);
    detect_idx64<<<1, 64, 0, stream>>>(edge, flag);
    cvt_x_kernel<<<(NN * 26 + 255) / 256, 256, 0, stream>>>(x, xb);

    const int eb8 = (E + 2047) / 2048;
    rank_kernel<<<eb8, 256, 0, stream>>>(edge, E, flag, counts2, rank);
    scan_partial_kernel<<<SC_NB, 256, 0, stream>>>(counts2, blockSums);
    scan_bases_kernel<<<1, 256, 0, stream>>>(blockSums);
    scan_final_kernel<<<SC_NB, 256, 0, stream>>>(counts2, blockSums, keyoff);
    place_kernel<<<eb8, 256, 0, stream>>>(edge, E, flag, keyoff, rank, csr_src);

    const int gb = (NN + NPB - 1) / NPB;      // wave per node
    const int db = (NN + 255) / 256;          // lane per node

    // Layer 1: 50 -> 32, relu
    gather_kernel<25, 26><<<gb, 256, 0, stream>>>(xb, keyoff, csr_src, agg1);
    dense_kernel<50, 26, 26, 16, 0><<<db, 256, 0, stream>>>(agg1, xb, Wl1, bl1, Wr1, h1b);
    // Layer 2: 32 -> 32, relu
    gather_kernel<16, 16><<<gb, 256, 0, stream>>>(h1b, keyoff, csr_src, agg2);
    dense_kernel<32, 16, 16, 16, 0><<<db, 256, 0, stream>>>(agg2, h1b, Wl2, bl2, Wr2, h2b);
    // Layer 3: 32 -> 32, log_softmax -> fp32 d_out
    gather_kernel<16, 16><<<gb, 256, 0, stream>>>(h2b, keyoff, csr_src, agg3);
    dense_kernel<32, 16, 16, 0, 2><<<db, 256, 0, stream>>>(agg3, h2b, Wl3, bl3, Wr3, d_out);
}

// Round 15
// 410.016 us; speedup vs baseline: 1.0246x; 1.0246x over previous
//
#include <hip/hip_runtime.h>
#include <math.h>

#define NN 100000      // nodes
#define CD 32          // classes / hidden
#define NPB 4          // nodes (waves) per block in gather kernel

#define SCAN_EPB 512                                   // counts per scan block
#define SCAN_NB  ((NN + SCAN_EPB - 1) / SCAN_EPB)      // 196 blocks

typedef unsigned int   uint32;
typedef unsigned short ushort16;

// fp32 -> bf16 round-to-nearest-even
__device__ __forceinline__ ushort16 f2b(float f) {
    uint32 u = __float_as_uint(f);
    u = (u + 0x7FFFu + ((u >> 16) & 1u)) >> 16;
    return (ushort16)u;
}
// packed bf16 pair -> two fp32 (exact)
__device__ __forceinline__ float b2f_lo(uint32 u) { return __uint_as_float(u << 16); }
__device__ __forceinline__ float b2f_hi(uint32 u) { return __uint_as_float(u & 0xFFFF0000u); }

// ---------------------------------------------------------------------------
__global__ void detect_idx64(const void* edge, int* flag) {
    const long long* p = (const long long*)edge;
    int lane = threadIdx.x & 63;
    int bad = 0;
    for (int i = lane; i < 512; i += 64) {
        long long v = p[i];
        if (v < 0 || v >= NN) bad = 1;
    }
    unsigned long long anybad = __ballot(bad);
    if (lane == 0) *flag = (anybad == 0ULL) ? 1 : 0;
}

__device__ __forceinline__ int load_idx(const void* edge, int i, int is64) {
    if (is64) return (int)((const long long*)edge)[i];
    return ((const int*)edge)[i];
}

// ---------------------------------------------------------------------------
// x (fp32, NN x 50) -> packed bf16 rows, stride 26 uints (uint 25 = zero pad).
__global__ void cvt_x_kernel(const float* __restrict__ x, uint32* __restrict__ xb) {
    const int t = blockIdx.x * blockDim.x + threadIdx.x;
    if (t >= NN * 26) return;
    const int n = t / 26;
    const int c = t - n * 26;
    if (c == 25) { xb[t] = 0; return; }
    float2 v = *(const float2*)&x[n * 50 + 2 * c];
    xb[t] = (uint32)f2b(v.x) | ((uint32)f2b(v.y) << 16);
}

// ---------------------------------------------------------------------------
// CSR build, single atomic pass (R13-proven; R14 showed the 1.6M returning
// atomics sit at the chip-wide atomic command-rate wall — replication of
// counters does NOT help, so keep the simple packed form).
__global__ void rank_kernel(const void* edge, int E, const int* flag,
                            int* counts, int* __restrict__ rank) {
    const int is64 = *flag;
    const int e0   = blockIdx.x * (blockDim.x * 8) + threadIdx.x;
    int  d[8], r[8];
    bool v[8];
#pragma unroll
    for (int k = 0; k < 8; ++k) {
        int e = e0 + k * 256;
        v[k] = e < E;
        if (v[k]) d[k] = load_idx(edge, E + e, is64);
    }
#pragma unroll
    for (int k = 0; k < 8; ++k)
        if (v[k]) r[k] = atomicAdd(&counts[d[k]], 1);
#pragma unroll
    for (int k = 0; k < 8; ++k)
        if (v[k]) rank[e0 + k * 256] = r[k];
}

__global__ void scan_partial_kernel(const int* __restrict__ counts,
                                    int* __restrict__ blockSums) {
    __shared__ int red[256];
    const int b = blockIdx.x, t = threadIdx.x;
    const int base = b * SCAN_EPB + t * 2;
    int s = 0;
    if (base < NN)     s += counts[base];
    if (base + 1 < NN) s += counts[base + 1];
    red[t] = s;
    __syncthreads();
    for (int off = 128; off > 0; off >>= 1) {
        if (t < off) red[t] += red[t + off];
        __syncthreads();
    }
    if (t == 0) blockSums[b] = red[0];
}

__global__ void scan_bases_kernel(int* blockSums) {
    __shared__ int tmp[SCAN_NB];
    const int t = threadIdx.x;
    if (t < SCAN_NB) tmp[t] = blockSums[t];
    __syncthreads();
    if (t == 0) {
        int run = 0;
        for (int i = 0; i < SCAN_NB; ++i) { int c = tmp[i]; tmp[i] = run; run += c; }
    }
    __syncthreads();
    if (t < SCAN_NB) blockSums[t] = tmp[t];
}

__global__ void scan_final_kernel(const int* __restrict__ counts,
                                  const int* __restrict__ blockSums,
                                  int* __restrict__ offsets) {
    __shared__ int tsum[256];
    const int b = blockIdx.x, t = threadIdx.x;
    const int base = b * SCAN_EPB + t * 2;
    const int c0 = (base < NN)     ? counts[base]     : 0;
    const int c1 = (base + 1 < NN) ? counts[base + 1] : 0;
    tsum[t] = c0 + c1;
    __syncthreads();
    for (int off = 1; off < 256; off <<= 1) {
        int u = (t >= off) ? tsum[t - off] : 0;
        __syncthreads();
        tsum[t] += u;
        __syncthreads();
    }
    const int bbase = blockSums[b];
    const int excl  = tsum[t] - (c0 + c1);
    if (base < NN) {
        offsets[base] = bbase + excl;
        if (base + 1 < NN) offsets[base + 1] = bbase + excl + c0;
    }
    if (b == SCAN_NB - 1 && t == 255) offsets[NN] = bbase + tsum[255];  // == E
}

// place: NO atomics — position is offsets[d] + rank[e].
__global__ void place_kernel(const void* edge, int E, const int* flag,
                             const int* __restrict__ offsets,
                             const int* __restrict__ rank,
                             int* __restrict__ csr_src) {
    const int is64 = *flag;
    const int e0   = blockIdx.x * (blockDim.x * 8) + threadIdx.x;
#pragma unroll
    for (int k = 0; k < 8; ++k) {
        int e = e0 + k * 256;
        if (e < E) {
            int s = load_idx(edge, e, is64);
            int d = load_idx(edge, E + e, is64);
            csr_src[offsets[d] + rank[e]] = s;
        }
    }
}

// ---------------------------------------------------------------------------
// Gather-max kernels (bf16). R13's DIN=32 mapping left lanes j>=16 idle —
// half the wave's load slots wasted. Fix: quarter-wave (4 edges x 16 chunks,
// all 64 lanes issue) x unroll 4 = 16 edges in flight. Layer 1 (CW=25):
// half-wave x unroll 8 = 16 edges in flight.
__global__ void gather50_kernel(const uint32* __restrict__ hb,
                                const int* __restrict__ offsets,
                                const int* __restrict__ csr_src,
                                uint32* __restrict__ aggB) {
    const int tid  = threadIdx.x;
    const int g    = tid >> 6;
    const int lane = tid & 63;
    const int p    = lane >> 5;
    const int j    = lane & 31;
    const bool ac  = (j < 25);
    const int n    = blockIdx.x * NPB + g;
    if (n >= NN) return;

    const float NEG = -INFINITY;
    const int beg = offsets[n];
    const int end = offsets[n + 1];

    float lo_[8], hi_[8];
#pragma unroll
    for (int k = 0; k < 8; ++k) { lo_[k] = NEG; hi_[k] = NEG; }
    int i = beg + p;
    for (; i + 14 < end; i += 16) {
        int s[8];
#pragma unroll
        for (int k = 0; k < 8; ++k) s[k] = csr_src[i + 2 * k];
        if (ac) {
#pragma unroll
            for (int k = 0; k < 8; ++k) {
                uint32 u = hb[(size_t)s[k] * 26 + j];
                lo_[k] = fmaxf(lo_[k], b2f_lo(u));
                hi_[k] = fmaxf(hi_[k], b2f_hi(u));
            }
        }
    }
    if (ac) {
#pragma unroll
        for (int k = 0; k < 7; ++k) {
            if (i + 2 * k < end) {
                uint32 u = hb[(size_t)csr_src[i + 2 * k] * 26 + j];
                lo_[k] = fmaxf(lo_[k], b2f_lo(u));
                hi_[k] = fmaxf(hi_[k], b2f_hi(u));
            }
        }
    }
#pragma unroll
    for (int off2 = 4; off2 > 0; off2 >>= 1)
#pragma unroll
        for (int k = 0; k < off2; ++k) {
            lo_[k] = fmaxf(lo_[k], lo_[k + off2]);
            hi_[k] = fmaxf(hi_[k], hi_[k + off2]);
        }
    float lo = lo_[0], hi = hi_[0];
    lo = fmaxf(lo, __shfl_xor(lo, 32));
    hi = fmaxf(hi, __shfl_xor(hi, 32));
    lo = (lo == NEG) ? 0.0f : lo;
    hi = (hi == NEG) ? 0.0f : hi;
    if (p == 0 && ac) {
        aggB[(size_t)n * 26 + j] =
            (__float_as_uint(lo) >> 16) | (__float_as_uint(hi) & 0xFFFF0000u);
    }
}

__global__ void gather32_kernel(const uint32* __restrict__ hb,
                                const int* __restrict__ offsets,
                                const int* __restrict__ csr_src,
                                uint32* __restrict__ aggB) {
    const int tid  = threadIdx.x;
    const int g    = tid >> 6;
    const int lane = tid & 63;
    const int e    = lane >> 4;        // edge slot 0..3
    const int c    = lane & 15;        // uint chunk
    const int n    = blockIdx.x * NPB + g;
    if (n >= NN) return;

    const float NEG = -INFINITY;
    const int beg = offsets[n];
    const int end = offsets[n + 1];

    float l0 = NEG, h0 = NEG, l1 = NEG, h1 = NEG;
    float l2 = NEG, h2 = NEG, l3 = NEG, h3 = NEG;
    int i = beg + e;
    for (; i + 12 < end; i += 16) {    // 16 edges per iter, all lanes active
        int s0 = csr_src[i];
        int s1 = csr_src[i + 4];
        int s2 = csr_src[i + 8];
        int s3 = csr_src[i + 12];
        uint32 u0 = hb[(size_t)s0 * 16 + c];
        uint32 u1 = hb[(size_t)s1 * 16 + c];
        uint32 u2 = hb[(size_t)s2 * 16 + c];
        uint32 u3 = hb[(size_t)s3 * 16 + c];
        l0 = fmaxf(l0, b2f_lo(u0)); h0 = fmaxf(h0, b2f_hi(u0));
        l1 = fmaxf(l1, b2f_lo(u1)); h1 = fmaxf(h1, b2f_hi(u1));
        l2 = fmaxf(l2, b2f_lo(u2)); h2 = fmaxf(h2, b2f_hi(u2));
        l3 = fmaxf(l3, b2f_lo(u3)); h3 = fmaxf(h3, b2f_hi(u3));
    }
    if (i < end) {
        uint32 u = hb[(size_t)csr_src[i] * 16 + c];
        l0 = fmaxf(l0, b2f_lo(u)); h0 = fmaxf(h0, b2f_hi(u));
    }
    if (i + 4 < end) {
        uint32 u = hb[(size_t)csr_src[i + 4] * 16 + c];
        l1 = fmaxf(l1, b2f_lo(u)); h1 = fmaxf(h1, b2f_hi(u));
    }
    if (i + 8 < end) {
        uint32 u = hb[(size_t)csr_src[i + 8] * 16 + c];
        l2 = fmaxf(l2, b2f_lo(u)); h2 = fmaxf(h2, b2f_hi(u));
    }
    float lo = fmaxf(fmaxf(l0, l1), fmaxf(l2, l3));
    float hi = fmaxf(fmaxf(h0, h1), fmaxf(h2, h3));
    lo = fmaxf(lo, __shfl_xor(lo, 16));   // combine edge slots 0<->1, 2<->3
    hi = fmaxf(hi, __shfl_xor(hi, 16));
    lo = fmaxf(lo, __shfl_xor(lo, 32));   // combine pairs
    hi = fmaxf(hi, __shfl_xor(hi, 32));
    lo = (lo == NEG) ? 0.0f : lo;
    hi = (hi == NEG) ? 0.0f : hi;
    if (lane < 16) {
        aggB[(size_t)n * 16 + lane] =
            (__float_as_uint(lo) >> 16) | (__float_as_uint(hi) & 0xFFFF0000u);
    }
}

// ---------------------------------------------------------------------------
// Dense kernel (R11-proven): one lane per node; 32 fp32 accumulators; wave-
// uniform weight addresses scalarize to s_load. MODE 0 = relu -> bf16;
// 2 = log_softmax -> fp32 (lane-local epilogue).
template <int DIN, int ASTR, int HSTR, int OSTR, int MODE>
__global__ void dense_kernel(const uint32* __restrict__ aggB,
                             const uint32* __restrict__ hB,
                             const float* __restrict__ Wl,
                             const float* __restrict__ bl,
                             const float* __restrict__ Wr,
                             void* __restrict__ out_v) {
    const int n = blockIdx.x * blockDim.x + threadIdx.x;
    if (n >= NN) return;

    float acc[CD];
#pragma unroll
    for (int j = 0; j < CD; ++j) acc[j] = bl[j];

    {
        const uint32* row = aggB + (size_t)n * ASTR;
        for (int c = 0; c < DIN / 4; ++c) {
            uint2 u = *(const uint2*)&row[c * 2];
            float d0 = b2f_lo(u.x), d1 = b2f_hi(u.x);
            float d2 = b2f_lo(u.y), d3 = b2f_hi(u.y);
            const float* w = Wl + c * 4 * CD;
#pragma unroll
            for (int j = 0; j < CD; ++j)
                acc[j] += d0 * w[j] + d1 * w[CD + j] + d2 * w[2 * CD + j] + d3 * w[3 * CD + j];
        }
        if (DIN % 4) {
            uint32 u = row[(DIN / 4) * 2];
            float d0 = b2f_lo(u), d1 = b2f_hi(u);
            const float* w = Wl + (DIN - 2) * CD;
#pragma unroll
            for (int j = 0; j < CD; ++j)
                acc[j] += d0 * w[j] + d1 * w[CD + j];
        }
    }
    {
        const uint32* row = hB + (size_t)n * HSTR;
        for (int c = 0; c < DIN / 4; ++c) {
            uint2 u = *(const uint2*)&row[c * 2];
            float d0 = b2f_lo(u.x), d1 = b2f_hi(u.x);
            float d2 = b2f_lo(u.y), d3 = b2f_hi(u.y);
            const float* w = Wr + c * 4 * CD;
#pragma unroll
            for (int j = 0; j < CD; ++j)
                acc[j] += d0 * w[j] + d1 * w[CD + j] + d2 * w[2 * CD + j] + d3 * w[3 * CD + j];
        }
        if (DIN % 4) {
            uint32 u = row[(DIN / 4) * 2];
            float d0 = b2f_lo(u), d1 = b2f_hi(u);
            const float* w = Wr + (DIN - 2) * CD;
#pragma unroll
            for (int j = 0; j < CD; ++j)
                acc[j] += d0 * w[j] + d1 * w[CD + j];
        }
    }

    if (MODE == 0) {
        uint32* orow = (uint32*)out_v + (size_t)n * OSTR;
#pragma unroll
        for (int c = 0; c < CD / 2; ++c) {
            float a0 = fmaxf(acc[2 * c],     0.0f);
            float a1 = fmaxf(acc[2 * c + 1], 0.0f);
            orow[c] = (uint32)f2b(a0) | ((uint32)f2b(a1) << 16);
        }
    } else {
        float m = acc[0];
#pragma unroll
        for (int j = 1; j < CD; ++j) m = fmaxf(m, acc[j]);
        float s = 0.0f;
#pragma unroll
        for (int j = 0; j < CD; ++j) s += expf(acc[j] - m);
        const float lse = m + logf(s);
        float* orow = (float*)out_v + (size_t)n * CD;
#pragma unroll
        for (int j = 0; j < CD; ++j) orow[j] = acc[j] - lse;
    }
}

// ---------------------------------------------------------------------------
extern "C" void kernel_launch(void* const* d_in, const int* in_sizes, int n_in,
                              void* d_out, int out_size, void* d_ws, size_t ws_size,
                              hipStream_t stream) {
    const float* x    = (const float*)d_in[0];
    const void*  edge = d_in[1];
    const float* Wl1 = (const float*)d_in[2];
    const float* bl1 = (const float*)d_in[3];
    const float* Wr1 = (const float*)d_in[4];
    const float* Wl2 = (const float*)d_in[5];
    const float* bl2 = (const float*)d_in[6];
    const float* Wr2 = (const float*)d_in[7];
    const float* Wl3 = (const float*)d_in[8];
    const float* bl3 = (const float*)d_in[9];
    const float* Wr3 = (const float*)d_in[10];

    const int E = in_sizes[1] / 2;

    // Workspace carve-up (256B aligned). Total ≈ 24.0 MB (R13-proven layout).
    // rank[] lives in d_out (dead before agg1 is written there); h2b reuses
    // xb (dead after dense-L1); agg3 reuses h1b (dead after dense-L2).
    char* ws = (char*)d_ws;
    size_t off = 0;
    auto carve = [&](size_t bytes) {
        void* p = ws + off;
        off = (off + bytes + 255) & ~(size_t)255;
        return p;
    };
    int*    counts    = (int*)   carve((size_t)NN * 4);
    int*    offsets   = (int*)   carve((size_t)(NN + 1) * 4);
    int*    flag      = (int*)   carve(4);
    int*    blockSums = (int*)   carve((size_t)SCAN_NB * 4);
    int*    csr_src   = (int*)   carve((size_t)E * 4);
    uint32* xb        = (uint32*)carve((size_t)NN * 26 * 4);  // 10.4 MB
    uint32* h1b       = (uint32*)carve((size_t)NN * 16 * 4);  // 6.4 MB
    (void)ws_size; (void)n_in; (void)out_size;

    int*    rank = (int*)d_out;            // 6.4 MB, dead before agg1
    uint32* agg1 = (uint32*)d_out;         // L1 agg, stride 26
    uint32* agg2 = (uint32*)d_out;         // L2 agg, stride 16
    uint32* h2b  = xb;                     // xb dead after dense-L1
    uint32* agg3 = h1b;                    // h1b dead after dense-L2

    hipMemsetAsync(counts, 0, (size_t)NN * 4, stream);
    detect_idx64<<<1, 64, 0, stream>>>(edge, flag);
    cvt_x_kernel<<<(NN * 26 + 255) / 256, 256, 0, stream>>>(x, xb);

    const int eb8 = (E + 2047) / 2048;
    rank_kernel<<<eb8, 256, 0, stream>>>(edge, E, flag, counts, rank);
    scan_partial_kernel<<<SCAN_NB, 256, 0, stream>>>(counts, blockSums);
    scan_bases_kernel<<<1, 256, 0, stream>>>(blockSums);
    scan_final_kernel<<<SCAN_NB, 256, 0, stream>>>(counts, blockSums, offsets);
    place_kernel<<<eb8, 256, 0, stream>>>(edge, E, flag, offsets, rank, csr_src);

    const int gb = (NN + NPB - 1) / NPB;      // wave per node
    const int db = (NN + 255) / 256;          // lane per node

    // Layer 1: 50 -> 32, relu
    gather50_kernel<<<gb, 256, 0, stream>>>(xb, offsets, csr_src, agg1);
    dense_kernel<50, 26, 26, 16, 0><<<db, 256, 0, stream>>>(agg1, xb, Wl1, bl1, Wr1, h1b);
    // Layer 2: 32 -> 32, relu
    gather32_kernel<<<gb, 256, 0, stream>>>(h1b, offsets, csr_src, agg2);
    dense_kernel<32, 16, 16, 16, 0><<<db, 256, 0, stream>>>(agg2, h1b, Wl2, bl2, Wr2, h2b);
    // Layer 3: 32 -> 32, log_softmax -> fp32 d_out
    gather32_kernel<<<gb, 256, 0, stream>>>(h2b, offsets, csr_src, agg3);
    dense_kernel<32, 16, 16, 0, 2><<<db, 256, 0, stream>>>(agg3, h2b, Wl3, bl3, Wr3, d_out);
}